// Round 1
// baseline (631.909 us; speedup 1.0000x reference)
//
#include <hip/hip_runtime.h>

#define NF     256
#define NPAIRS 32640
#define OUTW   (NF + NPAIRS)   // 32896
#define BATCH  4096

// Pairs are combinations(range(256), 2) in lexicographic order (SAME_DIVIDER=1):
// segment i (i = 0..254) holds pairs (i, j) for j = i+1..255 at flat offset
// O(i) = sum_{k<i} (255-k). Lane t owns column j = t and keeps x[row][t] in a
// register; sx[i] is a wave-uniform broadcast LDS read (conflict-free).
__global__ __launch_bounds__(256)
void poly_features_kernel(const float* __restrict__ x,
                          const int*   __restrict__ idx_a,   // unused (analytic)
                          const int*   __restrict__ idx_b,   // unused (analytic)
                          float*       __restrict__ out)
{
    __shared__ float sx[NF];

    const int b = blockIdx.x;
    const int t = threadIdx.x;

    const float v = x[(size_t)b * NF + t];   // coalesced row load
    sx[t] = v;

    float* __restrict__ orow = out + (size_t)b * OUTW;
    orow[t] = v;                             // identity part, coalesced

    __syncthreads();

    float* __restrict__ ox = orow + NF;
    // Per-lane fixed part of the store address; uniform part (off - i - 1)
    // stays scalar so the compiler folds it into the SGPR base.
    float* __restrict__ pt = ox + t;

    int off = 0;                             // wave-uniform flat segment offset
    for (int i0 = 0; i0 < 256; i0 += 4) {
        // broadcast read of 4 segment scalars: one ds_read_b128, same addr
        // across all lanes -> no bank conflicts
        const float4 s4 = *(const float4*)(&sx[i0]);
        const float si[4] = {s4.x, s4.y, s4.z, s4.w};
        #pragma unroll
        for (int k = 0; k < 4; ++k) {
            const int i = i0 + k;
            if (t > i) {
                // pair (i, t) -> ox[off + (t - i - 1)], lane-contiguous store
                pt[off - i - 1] = si[k] * v;
            }
            off += 255 - i;                  // uniform scalar update
        }
    }
}

extern "C" void kernel_launch(void* const* d_in, const int* in_sizes, int n_in,
                              void* d_out, int out_size, void* d_ws, size_t ws_size,
                              hipStream_t stream) {
    const float* x     = (const float*)d_in[0];
    const int*   idx_a = (const int*)d_in[1];
    const int*   idx_b = (const int*)d_in[2];
    float*       out   = (float*)d_out;

    poly_features_kernel<<<BATCH, 256, 0, stream>>>(x, idx_a, idx_b, out);
}

// Round 2
// 553.368 us; speedup vs baseline: 1.1419x; 1.1419x over previous
//
#include <hip/hip_runtime.h>

#define NF     256
#define NPAIRS 32640
#define OUTW   (NF + NPAIRS)   // 32896
#define BATCH  4096
#define NREP   8
#define REPW   257             // 257 ≡ 1 (mod 32): replica r rotates banks by r

__global__ __launch_bounds__(256)
void poly_features_kernel(const float* __restrict__ x,
                          const int*   __restrict__ idx_a,
                          const int*   __restrict__ idx_b,
                          float*       __restrict__ out)
{
    // 8 bank-rotated replicas of the row. Gather pattern is stride-4 across
    // lanes (8-way conflict on a single copy); replica (lane>>3)&7 puts the
    // 8 colliding lanes on 8 distinct banks -> 2 lanes/bank = conflict-free.
    __shared__ float sx[NREP * REPW];

    const int b = blockIdx.x;
    const int t = threadIdx.x;

    const float v = x[(size_t)b * NF + t];   // coalesced row load
    #pragma unroll
    for (int r = 0; r < NREP; ++r)
        sx[r * REPW + t] = v;                // stride-1 writes, conflict-free

    float* __restrict__ orow = out + (size_t)b * OUTW;
    orow[t] = v;                             // identity part, coalesced

    __syncthreads();

    const float* __restrict__ sxr = sx + ((t >> 3) & 7) * REPW;

    const int4* ia4 = (const int4*)idx_a;
    const int4* ib4 = (const int4*)idx_b;
    float4* o4 = (float4*)(orow + NF);       // (b*32896+256)*4 % 16 == 0

    #pragma unroll 4
    for (int g = t; g < NPAIRS / 4; g += 256) {
        int4 ia = ia4[g];
        int4 ib = ib4[g];
        float4 r;
        r.x = sxr[ia.x] * sxr[ib.x];
        r.y = sxr[ia.y] * sxr[ib.y];
        r.z = sxr[ia.z] * sxr[ib.z];
        r.w = sxr[ia.w] * sxr[ib.w];
        o4[g] = r;                           // dense aligned 16B store
    }
}

extern "C" void kernel_launch(void* const* d_in, const int* in_sizes, int n_in,
                              void* d_out, int out_size, void* d_ws, size_t ws_size,
                              hipStream_t stream) {
    const float* x     = (const float*)d_in[0];
    const int*   idx_a = (const int*)d_in[1];
    const int*   idx_b = (const int*)d_in[2];
    float*       out   = (float*)d_out;

    poly_features_kernel<<<BATCH, 256, 0, stream>>>(x, idx_a, idx_b, out);
}

// Round 4
// 541.928 us; speedup vs baseline: 1.1660x; 1.0211x over previous
//
#include <hip/hip_runtime.h>

#define NF     256
#define NPAIRS 32640
#define OUTW   (NF + NPAIRS)   // 32896
#define BATCH  4096
#define NREP   8
#define REPW   257             // 257 ≡ 1 (mod 32): replica r rotates banks by r

// Native clang vector type: __builtin_nontemporal_store requires a pointer to
// integer/float/vector-of-such, not HIP's float4 class type.
typedef float f32x4 __attribute__((ext_vector_type(4)));

__global__ __launch_bounds__(256)
void poly_features_kernel(const float* __restrict__ x,
                          const int*   __restrict__ idx_a,
                          const int*   __restrict__ idx_b,
                          float*       __restrict__ out)
{
    // 8 bank-rotated replicas of the row (kept from R2 — neutral, not harmful).
    __shared__ float sx[NREP * REPW];

    const int b = blockIdx.x;
    const int t = threadIdx.x;

    const float v = x[(size_t)b * NF + t];   // coalesced row load
    #pragma unroll
    for (int r = 0; r < NREP; ++r)
        sx[r * REPW + t] = v;

    float* __restrict__ orow = out + (size_t)b * OUTW;
    __builtin_nontemporal_store(v, &orow[t]);   // identity part, streamed

    __syncthreads();

    const float* __restrict__ sxr = sx + ((t >> 3) & 7) * REPW;

    const int4* ia4 = (const int4*)idx_a;
    const int4* ib4 = (const int4*)idx_b;
    f32x4* o4 = (f32x4*)(orow + NF);         // (b*32896+256)*4 % 16 == 0

    #pragma unroll 4
    for (int g = t; g < NPAIRS / 4; g += 256) {
        int4 ia = ia4[g];
        int4 ib = ib4[g];
        f32x4 r;
        r.x = sxr[ia.x] * sxr[ib.x];
        r.y = sxr[ia.y] * sxr[ib.y];
        r.z = sxr[ia.z] * sxr[ib.z];
        r.w = sxr[ia.w] * sxr[ib.w];
        // Nontemporal: stream the 16B store, no L2 read-allocate of the line.
        __builtin_nontemporal_store(r, &o4[g]);
    }
}

extern "C" void kernel_launch(void* const* d_in, const int* in_sizes, int n_in,
                              void* d_out, int out_size, void* d_ws, size_t ws_size,
                              hipStream_t stream) {
    const float* x     = (const float*)d_in[0];
    const int*   idx_a = (const int*)d_in[1];
    const int*   idx_b = (const int*)d_in[2];
    float*       out   = (float*)d_out;

    poly_features_kernel<<<BATCH, 256, 0, stream>>>(x, idx_a, idx_b, out);
}